// Round 18
// baseline (150.972 us; speedup 1.0000x reference)
//
#include <hip/hip_runtime.h>
#include <hip/hip_fp16.h>
#include <math.h>

#define N_NODES    100000
#define N_EDGES    3200000
#define NUM_GRAPHS 512
#define D_IN       7
#define D_H        16
#define D_H2       8                           // half2 words per node row (16 feats)
#define SHIFT      7
#define BWIDTH     128                         // cols per bucket
#define NB         782                         // ceil(N_NODES / BWIDTH)
#define CHUNK      8192
#define NCH        391                         // ceil(N_EDGES / CHUNK)
#define PC         2                           // chunks per thread (colscan)
#define PB         2                           // buckets per thread (place, 512 thr)
#define TPH        36                          // words/feature-word row per half (%4==0)
#define HST        (8 * TPH)                   // 288 words per half (pull2, 8-word rows)
#define TP1        36
#define HST1       (4 * TP1)                   // 144 words per half (pull1, 4-word rows)

// ---- pass A: per-chunk bucket histograms (int4 loads) ----
__global__ void hist_kernel(const int* __restrict__ col, int* __restrict__ cnt) {
    __shared__ int lh[NB];
    int tid = threadIdx.x;
    for (int i = tid; i < NB; i += blockDim.x) lh[i] = 0;
    __syncthreads();
    int e0 = blockIdx.x * CHUNK;
    int n  = N_EDGES - e0; if (n > CHUNK) n = CHUNK;
    const int4* cp = (const int4*)(col + e0);
    int n4 = n >> 2;
    for (int q = tid; q < n4; q += blockDim.x) {
        int4 v = cp[q];
        atomicAdd(&lh[v.x >> SHIFT], 1);
        atomicAdd(&lh[v.y >> SHIFT], 1);
        atomicAdd(&lh[v.z >> SHIFT], 1);
        atomicAdd(&lh[v.w >> SHIFT], 1);
    }
    __syncthreads();
    int* outp = cnt + (size_t)blockIdx.x * NB;
    for (int i = tid; i < NB; i += blockDim.x) outp[i] = lh[i];
}

// ---- pass B: per-bucket exclusive scan over chunks ----
__global__ void colscan_kernel(const int* __restrict__ cnt, int* __restrict__ base,
                               int* __restrict__ bcnt) {
    __shared__ int ts[256];
    int b = blockIdx.x;
    int tid = threadIdx.x;
    int c0 = tid * PC;
    int vals[PC];
    int sum = 0;
#pragma unroll
    for (int q = 0; q < PC; ++q) {
        int c = c0 + q;
        int v = (c < NCH) ? cnt[(size_t)c * NB + b] : 0;
        vals[q] = v; sum += v;
    }
    ts[tid] = sum;
    __syncthreads();
    for (int st = 1; st < 256; st <<= 1) {
        int v = (tid >= st) ? ts[tid - st] : 0;
        __syncthreads();
        ts[tid] += v;
        __syncthreads();
    }
    int run = ts[tid] - sum;
    int* bp = base + (size_t)b * NCH;
#pragma unroll
    for (int q = 0; q < PC; ++q) {
        int c = c0 + q;
        if (c < NCH) { bp[c] = run; run += vals[q]; }
    }
    if (tid == 0) bcnt[b] = ts[255];
}

// ---- pass C: exclusive scan of bucket totals -> offs ----
__global__ void scan_kernel(const int* __restrict__ bcnt, int* __restrict__ offs) {
    __shared__ int lds[1024];
    int tid = threadIdx.x;
    lds[tid] = (tid < NB) ? bcnt[tid] : 0;
    __syncthreads();
    for (int st = 1; st < 1024; st <<= 1) {
        int v = (tid >= st) ? lds[tid - st] : 0;
        __syncthreads();
        lds[tid] += v;
        __syncthreads();
    }
    if (tid < NB) offs[tid + 1] = lds[tid];
    if (tid == 0) offs[0] = 0;
}

// ---- pass D: place (512 threads, CHUNK=8192, int4 loads) ----
__global__ void place_kernel(const int* __restrict__ row, const int* __restrict__ col,
                             const int* __restrict__ base, const int* __restrict__ offs,
                             int* __restrict__ part) {
    __shared__ int lh[NB];
    __shared__ int sc[NB];
    __shared__ int lb[NB];
    __shared__ int ts[512];
    __shared__ int stage[CHUNK];    // 32 KB
    __shared__ int dstv[CHUNK];     // 32 KB

    int c = blockIdx.x;
    int tid = threadIdx.x;
    int e0 = c * CHUNK;
    int n  = N_EDGES - e0; if (n > CHUNK) n = CHUNK;
    int n4 = n >> 2;
    const int4* cp = (const int4*)(col + e0);
    const int4* rp = (const int4*)(row + e0);

    for (int i = tid; i < NB; i += blockDim.x) lh[i] = 0;
    __syncthreads();
    for (int q = tid; q < n4; q += blockDim.x) {
        int4 v = cp[q];
        atomicAdd(&lh[v.x >> SHIFT], 1);
        atomicAdd(&lh[v.y >> SHIFT], 1);
        atomicAdd(&lh[v.z >> SHIFT], 1);
        atomicAdd(&lh[v.w >> SHIFT], 1);
    }
    __syncthreads();
    int b0 = tid * PB;
    int vals[PB];
    int sum = 0;
#pragma unroll
    for (int q = 0; q < PB; ++q) {
        int b = b0 + q;
        int v = (b < NB) ? lh[b] : 0;
        vals[q] = v; sum += v;
    }
    ts[tid] = sum;
    __syncthreads();
    for (int st = 1; st < 512; st <<= 1) {
        int v = (tid >= st) ? ts[tid - st] : 0;
        __syncthreads();
        ts[tid] += v;
        __syncthreads();
    }
    int run = ts[tid] - sum;
#pragma unroll
    for (int q = 0; q < PB; ++q) {
        int b = b0 + q;
        if (b < NB) {
            sc[b] = run;
            lb[b] = offs[b] + base[(size_t)b * NCH + c];
            run += vals[q];
            lh[b] = 0;
        }
    }
    __syncthreads();
    for (int q = tid; q < n4; q += blockDim.x) {
        int4 cc4 = cp[q];
        int4 rr4 = rp[q];
        int ccs[4] = { cc4.x, cc4.y, cc4.z, cc4.w };
        int rrs[4] = { rr4.x, rr4.y, rr4.z, rr4.w };
#pragma unroll
        for (int t = 0; t < 4; ++t) {
            int cc = ccs[t];
            int b = cc >> SHIFT;
            int rank = atomicAdd(&lh[b], 1);
            int loc = sc[b] + rank;
            stage[loc] = (rrs[t] << SHIFT) | (cc & (BWIDTH - 1));
            dstv[loc]  = lb[b] + rank;
        }
    }
    __syncthreads();
    for (int i = tid; i < n; i += blockDim.x)
        part[dstv[i]] = stage[i];
}

// ---- pass E: per-bucket CSR build + node_off/deg/dinv + xs pack + deg histogram ----
__global__ void csr_kernel(const int* __restrict__ part, const int* __restrict__ offs,
                           const float* __restrict__ x,
                           int* __restrict__ csr, int* __restrict__ node_off,
                           int* __restrict__ deg, float* __restrict__ dinv,
                           unsigned* __restrict__ xsh, int* __restrict__ dcnt) {
    __shared__ int cnt[BWIDTH];
    __shared__ int scn[BWIDTH];
    __shared__ int cur[BWIDTH];
    __shared__ int dh[128];
    int b = blockIdx.x;
    int o0 = offs[b], o1 = offs[b + 1];
    if (threadIdx.x < BWIDTH) { cnt[threadIdx.x] = 0; dh[threadIdx.x] = 0; }
    __syncthreads();
    for (int j = o0 + threadIdx.x; j < o1; j += blockDim.x)
        atomicAdd(&cnt[part[j] & (BWIDTH - 1)], 1);
    __syncthreads();
    if (threadIdx.x < BWIDTH) scn[threadIdx.x] = cnt[threadIdx.x];
    __syncthreads();
    for (int st = 1; st < BWIDTH; st <<= 1) {
        int v = 0;
        if (threadIdx.x < BWIDTH && threadIdx.x >= st) v = scn[threadIdx.x - st];
        __syncthreads();
        if (threadIdx.x < BWIDTH) scn[threadIdx.x] += v;
        __syncthreads();
    }
    if (threadIdx.x < BWIDTH) {
        int excl = scn[threadIdx.x] - cnt[threadIdx.x];
        cur[threadIdx.x] = excl;
        int c = b * BWIDTH + threadIdx.x;
        if (c < N_NODES) {
            node_off[c] = o0 + excl;
            deg[c] = cnt[threadIdx.x];
            int bin = cnt[threadIdx.x]; if (bin > 127) bin = 127;
            atomicAdd(&dh[bin], 1);
            float dv = rsqrtf((float)cnt[threadIdx.x] + 1.0f);   // +1 self-loop
            dinv[c] = dv;
            float xv[8];
#pragma unroll
            for (int j = 0; j < D_IN; ++j) xv[j] = x[(size_t)c * D_IN + j] * dv;
            xv[7] = 0.f;
#pragma unroll
            for (int w = 0; w < 4; ++w) {
                __half2 p = __floats2half2_rn(xv[2 * w], xv[2 * w + 1]);
                xsh[(size_t)c * 4 + w] = *(unsigned*)&p;
            }
        }
    }
    __syncthreads();
    if (threadIdx.x < 128 && dh[threadIdx.x]) atomicAdd(&dcnt[threadIdx.x], dh[threadIdx.x]);
    for (int j = o0 + threadIdx.x; j < o1; j += blockDim.x) {
        int e = part[j];
        int l = e & (BWIDTH - 1);
        int pos = atomicAdd(&cur[l], 1);
        csr[o0 + pos] = e >> SHIFT;
    }
}

// ---- degree-bin exclusive scan -> cursors ----
__global__ void dscan_kernel(const int* __restrict__ dcnt, int* __restrict__ dcur) {
    __shared__ int s[128];
    int t = threadIdx.x;
    s[t] = dcnt[t];
    __syncthreads();
    for (int st = 1; st < 128; st <<= 1) {
        int v = (t >= st) ? s[t - st] : 0;
        __syncthreads();
        s[t] += v;
        __syncthreads();
    }
    dcur[t] = s[t] - dcnt[t];
}

// ---- counting-sort scatter: perm = nodes ordered by degree ----
__global__ void dperm_kernel(const int* __restrict__ deg, int* __restrict__ dcur,
                             int* __restrict__ perm) {
    __shared__ int lh[128];
    __shared__ int lb[128];
    int tid = threadIdx.x;
    if (tid < 128) lh[tid] = 0;
    __syncthreads();
    int v = blockIdx.x * 512 + tid;
    int bin = 0, rank = 0;
    if (v < N_NODES) {
        bin = deg[v]; if (bin > 127) bin = 127;
        rank = atomicAdd(&lh[bin], 1);
    }
    __syncthreads();
    if (tid < 128) lb[tid] = lh[tid] ? atomicAdd(&dcur[tid], lh[tid]) : 0;
    __syncthreads();
    if (v < N_NODES) perm[lb[bin] + rank] = v;
}

// ---- pull1: degree-paired 2 nodes/wave, 16B x-rows, reg-prefetch pipeline,
//      post-aggregation @W1 then fused @W2 ----
__global__ void __launch_bounds__(256, 8)
pull1_kernel(const unsigned* __restrict__ xsh, const int* __restrict__ csr,
             const int* __restrict__ node_off, const int* __restrict__ deg,
             const float* __restrict__ dinv, const float* __restrict__ b1,
             const float* __restrict__ W1, const float* __restrict__ W2,
             const int* __restrict__ perm, unsigned* __restrict__ s2h) {
    __shared__ unsigned stage[4][2 * HST1];   // 4608 B
    __shared__ float aggrow[4][2][8];
    __shared__ float hrow[4][2][D_H];
    int wave = threadIdx.x >> 6;
    int lane = threadIdx.x & 63;
    int h = lane >> 5, l = lane & 31;
    int v = perm[blockIdx.x * 8 + wave * 2 + h];
    int k = l & 15;
    float w1c[D_IN];
#pragma unroll
    for (int j = 0; j < D_IN; ++j) w1c[j] = W1[j * D_H + k];
    float w2c[D_H];
#pragma unroll
    for (int j = 0; j < D_H; ++j) w2c[j] = W2[j * D_H + k];
    int d = deg[v], o0 = node_off[v];
    unsigned* stg = stage[wave] + h * HST1;
    int rg = l >> 3, p = l & 7;
    int w = p >> 1;
    bool hi = (p & 1);
    const uint4* rp = (const uint4*)(stg + w * TP1 + rg * 8);
    float acc = 0.f;
    uint4 a = make_uint4(0u, 0u, 0u, 0u);
    if (l < d) {
        int r = __builtin_nontemporal_load(&csr[o0 + l]);
        a = *(const uint4*)(xsh + (size_t)r * 4);
    }
    for (int base = 0; base < d; base += 32) {
        uint4 an = make_uint4(0u, 0u, 0u, 0u);
        int jn = base + 32 + l;
        if (jn < d) {                          // prefetch next pass (issues early)
            int r = __builtin_nontemporal_load(&csr[o0 + jn]);
            an = *(const uint4*)(xsh + (size_t)r * 4);
        }
        asm volatile("s_waitcnt lgkmcnt(0)" ::: "memory");
        stg[0 * TP1 + l] = a.x;
        stg[1 * TP1 + l] = a.y;
        stg[2 * TP1 + l] = a.z;
        stg[3 * TP1 + l] = a.w;
        asm volatile("s_waitcnt lgkmcnt(0)" ::: "memory");
        uint4 q0 = rp[0], q1 = rp[1];
        unsigned ws[8] = { q0.x, q0.y, q0.z, q0.w, q1.x, q1.y, q1.z, q1.w };
#pragma unroll
        for (int i = 0; i < 8; ++i) {
            __half2 ph = *(__half2*)&ws[i];
            acc += hi ? __high2float(ph) : __low2float(ph);
        }
        a = an;
    }
    acc += __shfl_xor(acc, 8, 64);
    acc += __shfl_xor(acc, 16, 64);   // all 32 lanes: agg for x-feature p
    float dv = dinv[v];
    if (l < 8) aggrow[wave][h][l] = acc;
    asm volatile("s_waitcnt lgkmcnt(0)" ::: "memory");
    uint4 sx = *(const uint4*)(xsh + (size_t)v * 4);
    unsigned sxw[4] = { sx.x, sx.y, sx.z, sx.w };
    const float* ag = aggrow[wave][h];
    float hv = b1[k];
#pragma unroll
    for (int j = 0; j < D_IN; ++j) {
        __half2 ph = *(__half2*)&sxw[j >> 1];
        float xsv = (j & 1) ? __high2float(ph) : __low2float(ph);
        hv += dv * (ag[j] + xsv) * w1c[j];
    }
    hv = fmaxf(hv, 0.f);
    if (l < 16) hrow[wave][h][k] = hv;
    asm volatile("s_waitcnt lgkmcnt(0)" ::: "memory");
    const float4* hp = (const float4*)hrow[wave][h];
    float4 h0 = hp[0], h1 = hp[1], h2 = hp[2], h3 = hp[3];
    float a2 = h0.x * w2c[0] + h0.y * w2c[1] + h0.z * w2c[2] + h0.w * w2c[3]
             + h1.x * w2c[4] + h1.y * w2c[5] + h1.z * w2c[6] + h1.w * w2c[7]
             + h2.x * w2c[8] + h2.y * w2c[9] + h2.z * w2c[10] + h2.w * w2c[11]
             + h3.x * w2c[12] + h3.y * w2c[13] + h3.z * w2c[14] + h3.w * w2c[15];
    a2 *= dv;
    float a2hi = __shfl_xor(a2, 1, 64);
    if (l < 16 && (k & 1) == 0) {
        __half2 pq = __floats2half2_rn(a2, a2hi);
        s2h[(size_t)v * D_H2 + (k >> 1)] = *(unsigned*)&pq;
    }
}

// ---- pull2: degree-paired 2 nodes/wave, 32B s2-rows, reg-prefetch pipeline ----
__global__ void __launch_bounds__(256, 8)
pull2_kernel(const unsigned* __restrict__ sh, const int* __restrict__ csr,
             const int* __restrict__ node_off, const int* __restrict__ deg,
             const float* __restrict__ dinv, const float* __restrict__ b2,
             const int* __restrict__ perm, float* __restrict__ h2) {
    __shared__ unsigned stage[4][2 * HST];
    int wave = threadIdx.x >> 6;
    int lane = threadIdx.x & 63;
    int h = lane >> 5, l = lane & 31;
    int v = perm[blockIdx.x * 8 + wave * 2 + h];
    int k = l & 15;
    int d = deg[v], o0 = node_off[v];
    unsigned* stg = stage[wave] + h * HST;
    int g = l >> 4;
    const uint4* rp = (const uint4*)(stg + (k >> 1) * TPH + g * 16);
    bool hi = (k & 1);
    float acc = 0.f;
    uint4 a = make_uint4(0u, 0u, 0u, 0u), b = make_uint4(0u, 0u, 0u, 0u);
    if (l < d) {
        int r = __builtin_nontemporal_load(&csr[o0 + l]);
        const uint4* sp = (const uint4*)(sh + (size_t)r * D_H2);
        a = sp[0];
        b = sp[1];
    }
    for (int base = 0; base < d; base += 32) {
        uint4 an = make_uint4(0u, 0u, 0u, 0u), bn = make_uint4(0u, 0u, 0u, 0u);
        int jn = base + 32 + l;
        if (jn < d) {                          // prefetch next pass
            int r = __builtin_nontemporal_load(&csr[o0 + jn]);
            const uint4* sp = (const uint4*)(sh + (size_t)r * D_H2);
            an = sp[0];
            bn = sp[1];
        }
        asm volatile("s_waitcnt lgkmcnt(0)" ::: "memory");
        stg[0 * TPH + l] = a.x;
        stg[1 * TPH + l] = a.y;
        stg[2 * TPH + l] = a.z;
        stg[3 * TPH + l] = a.w;
        stg[4 * TPH + l] = b.x;
        stg[5 * TPH + l] = b.y;
        stg[6 * TPH + l] = b.z;
        stg[7 * TPH + l] = b.w;
        asm volatile("s_waitcnt lgkmcnt(0)" ::: "memory");
        uint4 q0 = rp[0], q1 = rp[1], q2 = rp[2], q3 = rp[3];
        unsigned ws[16] = { q0.x, q0.y, q0.z, q0.w, q1.x, q1.y, q1.z, q1.w,
                            q2.x, q2.y, q2.z, q2.w, q3.x, q3.y, q3.z, q3.w };
#pragma unroll
        for (int i = 0; i < 16; ++i) {
            __half2 p = *(__half2*)&ws[i];
            acc += hi ? __high2float(p) : __low2float(p);
        }
        a = an; b = bn;
    }
    acc += __shfl_xor(acc, 16, 64);
    if (l < 16) {
        float dv = dinv[v];
        unsigned wsv = sh[(size_t)v * D_H2 + (k >> 1)];
        __half2 ps = *(__half2*)&wsv;
        float selfv = (k & 1) ? __high2float(ps) : __low2float(ps);
        float o = dv * (acc + selfv) + b2[k];
        h2[(size_t)v * D_H + k] = fmaxf(o, 0.f);
    }
}

// one block per graph: boundaries via binary search on sorted batch, then
// mean-pool h rows and sigmoid(pool @ Wl + bl)
__global__ void pool_head_kernel(const float* __restrict__ h, const int* __restrict__ batch,
                                 const float* __restrict__ Wl, const float* __restrict__ bl,
                                 float* __restrict__ out) {
    int g = blockIdx.x;
    int lo = 0, hi = N_NODES;
    while (lo < hi) { int m = (lo + hi) >> 1; if (batch[m] < g) lo = m + 1; else hi = m; }
    int v0 = lo;
    int lo2 = v0, hi2 = N_NODES;
    while (lo2 < hi2) { int m = (lo2 + hi2) >> 1; if (batch[m] < g + 1) lo2 = m + 1; else hi2 = m; }
    int v1 = lo2;
    int k = threadIdx.x & 15;
    int vi = threadIdx.x >> 4;
    float acc = 0.f;
    for (int v = v0 + vi; v < v1; v += 16) acc += h[v * D_H + k];
    acc += __shfl_xor(acc, 16, 64);
    acc += __shfl_xor(acc, 32, 64);
    __shared__ float sm[4][D_H];
    int lane = threadIdx.x & 63;
    if (lane < 16) sm[threadIdx.x >> 6][k] = acc;
    __syncthreads();
    if (threadIdx.x < 16) {
        float tot = sm[0][k] + sm[1][k] + sm[2][k] + sm[3][k];
        float cntf = (float)(v1 - v0);
        tot /= fmaxf(cntf, 1.0f);
        float p = tot * Wl[k];
        p += __shfl_xor(p, 1, 64);
        p += __shfl_xor(p, 2, 64);
        p += __shfl_xor(p, 4, 64);
        p += __shfl_xor(p, 8, 64);
        if (k == 0) out[g] = 1.0f / (1.0f + expf(-(p + bl[0])));
    }
}

// ---------------- launch ----------------

extern "C" void kernel_launch(void* const* d_in, const int* in_sizes, int n_in,
                              void* d_out, int out_size, void* d_ws, size_t ws_size,
                              hipStream_t stream) {
    const float* x     = (const float*)d_in[0];
    const int*   ei    = (const int*)d_in[1];   // [2, E]: row then col
    const int*   batch = (const int*)d_in[2];
    const float* W1    = (const float*)d_in[3];
    const float* b1    = (const float*)d_in[4];
    const float* W2    = (const float*)d_in[5];
    const float* b2    = (const float*)d_in[6];
    const float* Wl    = (const float*)d_in[7];
    const float* bl    = (const float*)d_in[8];
    float* out = (float*)d_out;

    const int* row = ei;
    const int* col = ei + N_EDGES;

    // workspace layout. Region A is time-shared: {cnt,base} then csr.
    char* wsb = (char*)d_ws;
    size_t o = 0;
    int*      part     = (int*)(wsb + o);      o += (size_t)N_EDGES * 4;      // 12.8 MB
    char*     regionA  = wsb + o;              o += (size_t)N_EDGES * 4;      // 12.8 MB
    int*      cnt      = (int*)regionA;                                       // [NCH][NB]
    int*      base     = (int*)(regionA + (size_t)NCH * NB * 4);              // [NB][NCH]
    int*      csr      = (int*)regionA;                                       // after place
    int*      bcnt     = (int*)(wsb + o);      o += 1024 * 4;
    int*      offs     = (int*)(wsb + o);      o += 1024 * 4;
    int*      node_off = (int*)(wsb + o);      o += 100352 * 4;
    int*      deg      = (int*)(wsb + o);      o += 100352 * 4;
    float*    dinv     = (float*)(wsb + o);    o += 100352 * 4;
    unsigned* xsh      = (unsigned*)(wsb + o); o += (size_t)N_NODES * 4 * 4;    // 1.6 MB
    unsigned* sBh      = (unsigned*)(wsb + o); o += (size_t)N_NODES * D_H2 * 4; // 3.2 MB
    float*    h2       = (float*)(wsb + o);    o += (size_t)N_NODES * D_H * 4;  // 6.4 MB
    int*      dcnt     = (int*)(wsb + o);      o += 128 * 4;
    int*      dcur     = (int*)(wsb + o);      o += 128 * 4;
    int*      perm     = (int*)(wsb + o);      o += 100352 * 4;

    const int B = 256;

    // ---- build CSR via deterministic two-level scan (no global cursor atomics) ----
    hipMemsetAsync(dcnt, 0, 128 * sizeof(int), stream);
    hist_kernel<<<NCH, 512, 0, stream>>>(col, cnt);
    colscan_kernel<<<NB, B, 0, stream>>>(cnt, base, bcnt);
    scan_kernel<<<1, 1024, 0, stream>>>(bcnt, offs);
    place_kernel<<<NCH, 512, 0, stream>>>(row, col, base, offs, part);
    csr_kernel<<<NB, 512, 0, stream>>>(part, offs, x, csr, node_off, deg, dinv,
                                       xsh, dcnt);

    // ---- degree-paired schedule: perm = nodes sorted by degree ----
    dscan_kernel<<<1, 128, 0, stream>>>(dcnt, dcur);
    dperm_kernel<<<(N_NODES + 511) / 512, 512, 0, stream>>>(deg, dcur, perm);

    // ---- layer 1: x-space aggregation, fused @W1 + @W2 epilogue ----
    pull1_kernel<<<N_NODES / 8, B, 0, stream>>>(xsh, csr, node_off, deg, dinv,
                                                b1, W1, W2, perm, sBh);
    // ---- layer 2 ----
    pull2_kernel<<<N_NODES / 8, B, 0, stream>>>(sBh, csr, node_off, deg, dinv,
                                                b2, perm, h2);
    // ---- pool + head (boundaries via binary search) ----
    pool_head_kernel<<<NUM_GRAPHS, B, 0, stream>>>(h2, batch, Wl, bl, out);
}

// Round 19
// 131.565 us; speedup vs baseline: 1.1475x; 1.1475x over previous
//
#include <hip/hip_runtime.h>
#include <hip/hip_fp16.h>
#include <math.h>

#define N_NODES    100000
#define N_EDGES    3200000
#define NUM_GRAPHS 512
#define D_IN       7
#define D_H        16
#define D_H2       8                           // half2 words per node row (16 feats)
#define SHIFT      7
#define BWIDTH     128                         // cols per bucket
#define NB         782                         // ceil(N_NODES / BWIDTH)
#define CHUNK      8192
#define NCH        391                         // ceil(N_EDGES / CHUNK)
#define PC         2                           // chunks per thread (colscan)
#define PB         2                           // buckets per thread (place, 512 thr)
#define TPH        36                          // words/feature-word row per half (32+4; %4==0)
#define HST        (8 * TPH)                   // 288 words per half (pull2, 8-word rows)
#define TP1        36
#define HST1       (4 * TP1)                   // 144 words per half (pull1, 4-word rows)

// ---- pass A: per-chunk bucket histograms ----
__global__ void hist_kernel(const int* __restrict__ col, int* __restrict__ cnt) {
    __shared__ int lh[NB];
    int tid = threadIdx.x;
    for (int i = tid; i < NB; i += blockDim.x) lh[i] = 0;
    __syncthreads();
    int e0 = blockIdx.x * CHUNK;
    int e1 = e0 + CHUNK; if (e1 > N_EDGES) e1 = N_EDGES;
    for (int e = e0 + tid; e < e1; e += blockDim.x)
        atomicAdd(&lh[col[e] >> SHIFT], 1);
    __syncthreads();
    int* outp = cnt + (size_t)blockIdx.x * NB;
    for (int i = tid; i < NB; i += blockDim.x) outp[i] = lh[i];
}

// ---- pass B: per-bucket exclusive scan over chunks ----
__global__ void colscan_kernel(const int* __restrict__ cnt, int* __restrict__ base,
                               int* __restrict__ bcnt) {
    __shared__ int ts[256];
    int b = blockIdx.x;
    int tid = threadIdx.x;
    int c0 = tid * PC;
    int vals[PC];
    int sum = 0;
#pragma unroll
    for (int q = 0; q < PC; ++q) {
        int c = c0 + q;
        int v = (c < NCH) ? cnt[(size_t)c * NB + b] : 0;
        vals[q] = v; sum += v;
    }
    ts[tid] = sum;
    __syncthreads();
    for (int st = 1; st < 256; st <<= 1) {
        int v = (tid >= st) ? ts[tid - st] : 0;
        __syncthreads();
        ts[tid] += v;
        __syncthreads();
    }
    int run = ts[tid] - sum;
    int* bp = base + (size_t)b * NCH;
#pragma unroll
    for (int q = 0; q < PC; ++q) {
        int c = c0 + q;
        if (c < NCH) { bp[c] = run; run += vals[q]; }
    }
    if (tid == 0) bcnt[b] = ts[255];
}

// ---- pass C: exclusive scan of bucket totals -> offs ----
__global__ void scan_kernel(const int* __restrict__ bcnt, int* __restrict__ offs) {
    __shared__ int lds[1024];
    int tid = threadIdx.x;
    lds[tid] = (tid < NB) ? bcnt[tid] : 0;
    __syncthreads();
    for (int st = 1; st < 1024; st <<= 1) {
        int v = (tid >= st) ? lds[tid - st] : 0;
        __syncthreads();
        lds[tid] += v;
        __syncthreads();
    }
    if (tid < NB) offs[tid + 1] = lds[tid];
    if (tid == 0) offs[0] = 0;
}

// ---- pass D: place (512 threads, CHUNK=8192, ~76KB LDS) ----
__global__ void place_kernel(const int* __restrict__ row, const int* __restrict__ col,
                             const int* __restrict__ base, const int* __restrict__ offs,
                             int* __restrict__ part) {
    __shared__ int lh[NB];
    __shared__ int sc[NB];
    __shared__ int lb[NB];
    __shared__ int ts[512];
    __shared__ int stage[CHUNK];    // 32 KB
    __shared__ int dstv[CHUNK];     // 32 KB

    int c = blockIdx.x;
    int tid = threadIdx.x;
    int e0 = c * CHUNK;
    int e1 = e0 + CHUNK; if (e1 > N_EDGES) e1 = N_EDGES;
    int n  = e1 - e0;

    for (int i = tid; i < NB; i += blockDim.x) lh[i] = 0;
    __syncthreads();
    for (int e = e0 + tid; e < e1; e += blockDim.x)
        atomicAdd(&lh[col[e] >> SHIFT], 1);
    __syncthreads();
    int b0 = tid * PB;
    int vals[PB];
    int sum = 0;
#pragma unroll
    for (int q = 0; q < PB; ++q) {
        int b = b0 + q;
        int v = (b < NB) ? lh[b] : 0;
        vals[q] = v; sum += v;
    }
    ts[tid] = sum;
    __syncthreads();
    for (int st = 1; st < 512; st <<= 1) {
        int v = (tid >= st) ? ts[tid - st] : 0;
        __syncthreads();
        ts[tid] += v;
        __syncthreads();
    }
    int run = ts[tid] - sum;
#pragma unroll
    for (int q = 0; q < PB; ++q) {
        int b = b0 + q;
        if (b < NB) {
            sc[b] = run;
            lb[b] = offs[b] + base[(size_t)b * NCH + c];
            run += vals[q];
            lh[b] = 0;
        }
    }
    __syncthreads();
    for (int e = e0 + tid; e < e1; e += blockDim.x) {
        int cc = col[e];
        int b = cc >> SHIFT;
        int rank = atomicAdd(&lh[b], 1);
        int loc = sc[b] + rank;
        stage[loc] = (row[e] << SHIFT) | (cc & (BWIDTH - 1));
        dstv[loc]  = lb[b] + rank;
    }
    __syncthreads();
    for (int i = tid; i < n; i += blockDim.x)
        part[dstv[i]] = stage[i];
}

// ---- pass E: per-bucket CSR build + node_off/deg/dinv ----
__global__ void csr_kernel(const int* __restrict__ part, const int* __restrict__ offs,
                           int* __restrict__ csr, int* __restrict__ node_off,
                           int* __restrict__ deg, float* __restrict__ dinv) {
    __shared__ int cnt[BWIDTH];
    __shared__ int scn[BWIDTH];
    __shared__ int cur[BWIDTH];
    int b = blockIdx.x;
    int o0 = offs[b], o1 = offs[b + 1];
    if (threadIdx.x < BWIDTH) cnt[threadIdx.x] = 0;
    __syncthreads();
    for (int j = o0 + threadIdx.x; j < o1; j += blockDim.x)
        atomicAdd(&cnt[part[j] & (BWIDTH - 1)], 1);
    __syncthreads();
    if (threadIdx.x < BWIDTH) scn[threadIdx.x] = cnt[threadIdx.x];
    __syncthreads();
    for (int st = 1; st < BWIDTH; st <<= 1) {
        int v = 0;
        if (threadIdx.x < BWIDTH && threadIdx.x >= st) v = scn[threadIdx.x - st];
        __syncthreads();
        if (threadIdx.x < BWIDTH) scn[threadIdx.x] += v;
        __syncthreads();
    }
    if (threadIdx.x < BWIDTH) {
        int excl = scn[threadIdx.x] - cnt[threadIdx.x];
        cur[threadIdx.x] = excl;
        int c = b * BWIDTH + threadIdx.x;
        if (c < N_NODES) {
            node_off[c] = o0 + excl;
            deg[c] = cnt[threadIdx.x];
            dinv[c] = rsqrtf((float)cnt[threadIdx.x] + 1.0f);   // +1 self-loop
        }
    }
    __syncthreads();
    for (int j = o0 + threadIdx.x; j < o1; j += blockDim.x) {
        int e = part[j];
        int l = e & (BWIDTH - 1);
        int pos = atomicAdd(&cur[l], 1);
        csr[o0 + pos] = e >> SHIFT;
    }
}

// xs[v,:] = dinv[v] * x[v,:], packed 8 halves (7 feats + 0-pad) = 4 words/node
__global__ void xs_kernel(const float* __restrict__ x, const float* __restrict__ dinv,
                          unsigned* __restrict__ xsh) {
    int v = blockIdx.x * blockDim.x + threadIdx.x;
    if (v >= N_NODES) return;
    float dv = dinv[v];
    float xv[8];
#pragma unroll
    for (int j = 0; j < D_IN; ++j) xv[j] = x[v * D_IN + j] * dv;
    xv[7] = 0.f;
#pragma unroll
    for (int w = 0; w < 4; ++w) {
        __half2 p = __floats2half2_rn(xv[2 * w], xv[2 * w + 1]);
        xsh[(size_t)v * 4 + w] = *(unsigned*)&p;
    }
}

// ---- pull1: 2 nodes/wave, 16B x-rows, post-aggregation @W1 then @W2.
// h[v] = relu((dinv_v*(agg + xs_v)) @ W1 + b1);  s2 = dinv_v * (h @ W2)
__global__ void __launch_bounds__(256, 8)
pull1_kernel(const unsigned* __restrict__ xsh, const int* __restrict__ csr,
             const int* __restrict__ node_off, const int* __restrict__ deg,
             const float* __restrict__ dinv, const float* __restrict__ b1,
             const float* __restrict__ W1, const float* __restrict__ W2,
             unsigned* __restrict__ s2h) {
    __shared__ unsigned stage[4][2 * HST1];   // 4608 B
    __shared__ float aggrow[4][2][8];
    __shared__ float hrow[4][2][D_H];
    int wave = threadIdx.x >> 6;
    int lane = threadIdx.x & 63;
    int h = lane >> 5, l = lane & 31;
    int v = blockIdx.x * 8 + wave * 2 + h;
    int k = l & 15;
    float w1c[D_IN];
#pragma unroll
    for (int j = 0; j < D_IN; ++j) w1c[j] = W1[j * D_H + k];
    float w2c[D_H];
#pragma unroll
    for (int j = 0; j < D_H; ++j) w2c[j] = W2[j * D_H + k];
    int d = deg[v], o0 = node_off[v];
    unsigned* stg = stage[wave] + h * HST1;
    int rg = l >> 3, p = l & 7;
    int w = p >> 1;
    bool hi = (p & 1);
    const uint4* rp = (const uint4*)(stg + w * TP1 + rg * 8);
    float acc = 0.f;
    for (int base = 0; base < d; base += 32) {
        int j = base + l;
        uint4 a = make_uint4(0u, 0u, 0u, 0u);
        if (j < d) {
            int r = __builtin_nontemporal_load(&csr[o0 + j]);
            a = *(const uint4*)(xsh + (size_t)r * 4);
        }
        asm volatile("s_waitcnt lgkmcnt(0)" ::: "memory");
        stg[0 * TP1 + l] = a.x;
        stg[1 * TP1 + l] = a.y;
        stg[2 * TP1 + l] = a.z;
        stg[3 * TP1 + l] = a.w;
        asm volatile("s_waitcnt lgkmcnt(0)" ::: "memory");
        uint4 q0 = rp[0], q1 = rp[1];
        unsigned ws[8] = { q0.x, q0.y, q0.z, q0.w, q1.x, q1.y, q1.z, q1.w };
#pragma unroll
        for (int i = 0; i < 8; ++i) {
            __half2 ph = *(__half2*)&ws[i];
            acc += hi ? __high2float(ph) : __low2float(ph);
        }
    }
    acc += __shfl_xor(acc, 8, 64);
    acc += __shfl_xor(acc, 16, 64);   // all 32 lanes: agg for x-feature p
    float dv = dinv[v];
    if (l < 8) aggrow[wave][h][l] = acc;
    asm volatile("s_waitcnt lgkmcnt(0)" ::: "memory");
    uint4 sx = *(const uint4*)(xsh + (size_t)v * 4);
    unsigned sxw[4] = { sx.x, sx.y, sx.z, sx.w };
    const float* ag = aggrow[wave][h];
    float hv = b1[k];
#pragma unroll
    for (int j = 0; j < D_IN; ++j) {
        __half2 ph = *(__half2*)&sxw[j >> 1];
        float xsv = (j & 1) ? __high2float(ph) : __low2float(ph);
        hv += dv * (ag[j] + xsv) * w1c[j];
    }
    hv = fmaxf(hv, 0.f);
    if (l < 16) hrow[wave][h][k] = hv;
    asm volatile("s_waitcnt lgkmcnt(0)" ::: "memory");
    const float4* hp = (const float4*)hrow[wave][h];
    float4 h0 = hp[0], h1 = hp[1], h2 = hp[2], h3 = hp[3];
    float a2 = h0.x * w2c[0] + h0.y * w2c[1] + h0.z * w2c[2] + h0.w * w2c[3]
             + h1.x * w2c[4] + h1.y * w2c[5] + h1.z * w2c[6] + h1.w * w2c[7]
             + h2.x * w2c[8] + h2.y * w2c[9] + h2.z * w2c[10] + h2.w * w2c[11]
             + h3.x * w2c[12] + h3.y * w2c[13] + h3.z * w2c[14] + h3.w * w2c[15];
    a2 *= dv;
    float a2hi = __shfl_xor(a2, 1, 64);
    if (l < 16 && (k & 1) == 0) {
        __half2 pq = __floats2half2_rn(a2, a2hi);
        s2h[(size_t)v * D_H2 + (k >> 1)] = *(unsigned*)&pq;
    }
}

// ---- pull2 gather core: 2 nodes/wave, 32B s2-rows ----
__device__ __forceinline__ float gather_half(const unsigned* __restrict__ sh,
                                             const int* __restrict__ csr,
                                             int o0, int d, unsigned* stg, int l) {
    int g = l >> 4, k = l & 15;
    const uint4* rp = (const uint4*)(stg + (k >> 1) * TPH + g * 16);
    bool hi = (k & 1);
    float acc = 0.f;
    for (int base = 0; base < d; base += 32) {
        int j = base + l;
        uint4 a = make_uint4(0u, 0u, 0u, 0u), b = make_uint4(0u, 0u, 0u, 0u);
        if (j < d) {
            int r = __builtin_nontemporal_load(&csr[o0 + j]);
            const uint4* sp = (const uint4*)(sh + (size_t)r * D_H2);
            a = sp[0];
            b = sp[1];
        }
        asm volatile("s_waitcnt lgkmcnt(0)" ::: "memory");
        stg[0 * TPH + l] = a.x;
        stg[1 * TPH + l] = a.y;
        stg[2 * TPH + l] = a.z;
        stg[3 * TPH + l] = a.w;
        stg[4 * TPH + l] = b.x;
        stg[5 * TPH + l] = b.y;
        stg[6 * TPH + l] = b.z;
        stg[7 * TPH + l] = b.w;
        asm volatile("s_waitcnt lgkmcnt(0)" ::: "memory");
        uint4 q0 = rp[0], q1 = rp[1], q2 = rp[2], q3 = rp[3];
        unsigned ws[16] = { q0.x, q0.y, q0.z, q0.w, q1.x, q1.y, q1.z, q1.w,
                            q2.x, q2.y, q2.z, q2.w, q3.x, q3.y, q3.z, q3.w };
#pragma unroll
        for (int i = 0; i < 16; ++i) {
            __half2 p = *(__half2*)&ws[i];
            acc += hi ? __high2float(p) : __low2float(p);
        }
    }
    acc += __shfl_xor(acc, 16, 64);
    return acc;
}

// layer-2 pull (2 nodes/wave): h2 = relu(dinv*(gather+self)+b2), fp32 out
__global__ void __launch_bounds__(256, 8)
pull2_kernel(const unsigned* __restrict__ sh, const int* __restrict__ csr,
             const int* __restrict__ node_off, const int* __restrict__ deg,
             const float* __restrict__ dinv, const float* __restrict__ b2,
             float* __restrict__ h2) {
    __shared__ unsigned stage[4][2 * HST];
    int wave = threadIdx.x >> 6;
    int lane = threadIdx.x & 63;
    int h = lane >> 5, l = lane & 31;
    int v = blockIdx.x * 8 + wave * 2 + h;
    int k = l & 15;
    int d = deg[v], o0 = node_off[v];
    unsigned* stg = stage[wave] + h * HST;
    float acc = gather_half(sh, csr, o0, d, stg, l);
    if (l < 16) {
        float dv = dinv[v];
        unsigned ws = sh[(size_t)v * D_H2 + (k >> 1)];
        __half2 ps = *(__half2*)&ws;
        float selfv = (k & 1) ? __high2float(ps) : __low2float(ps);
        float o = dv * (acc + selfv) + b2[k];
        h2[(size_t)v * D_H + k] = fmaxf(o, 0.f);
    }
}

// batch sorted: starts[g] = first node of graph g
__global__ void starts_kernel(const int* __restrict__ batch, int* __restrict__ starts) {
    int v = blockIdx.x * blockDim.x + threadIdx.x;
    if (v >= N_NODES) return;
    int bv = batch[v];
    int prev = (v == 0) ? -1 : batch[v - 1];
    for (int g = prev + 1; g <= bv; ++g) starts[g] = v;
    if (v == N_NODES - 1) {
        for (int g = bv + 1; g <= NUM_GRAPHS; ++g) starts[g] = N_NODES;
    }
}

// one block per graph: mean-pool h rows then sigmoid(pool @ Wl + bl)
__global__ void pool_head_kernel(const float* __restrict__ h, const int* __restrict__ starts,
                                 const float* __restrict__ Wl, const float* __restrict__ bl,
                                 float* __restrict__ out) {
    int g = blockIdx.x;
    int v0 = starts[g], v1 = starts[g + 1];
    int k = threadIdx.x & 15;
    int vi = threadIdx.x >> 4;
    float acc = 0.f;
    for (int v = v0 + vi; v < v1; v += 16) acc += h[v * D_H + k];
    acc += __shfl_xor(acc, 16, 64);
    acc += __shfl_xor(acc, 32, 64);
    __shared__ float sm[4][D_H];
    int lane = threadIdx.x & 63;
    if (lane < 16) sm[threadIdx.x >> 6][k] = acc;
    __syncthreads();
    if (threadIdx.x < 16) {
        float tot = sm[0][k] + sm[1][k] + sm[2][k] + sm[3][k];
        float cntf = (float)(v1 - v0);
        tot /= fmaxf(cntf, 1.0f);
        float p = tot * Wl[k];
        p += __shfl_xor(p, 1, 64);
        p += __shfl_xor(p, 2, 64);
        p += __shfl_xor(p, 4, 64);
        p += __shfl_xor(p, 8, 64);
        if (k == 0) out[g] = 1.0f / (1.0f + expf(-(p + bl[0])));
    }
}

// ---------------- launch ----------------

extern "C" void kernel_launch(void* const* d_in, const int* in_sizes, int n_in,
                              void* d_out, int out_size, void* d_ws, size_t ws_size,
                              hipStream_t stream) {
    const float* x     = (const float*)d_in[0];
    const int*   ei    = (const int*)d_in[1];   // [2, E]: row then col
    const int*   batch = (const int*)d_in[2];
    const float* W1    = (const float*)d_in[3];
    const float* b1    = (const float*)d_in[4];
    const float* W2    = (const float*)d_in[5];
    const float* b2    = (const float*)d_in[6];
    const float* Wl    = (const float*)d_in[7];
    const float* bl    = (const float*)d_in[8];
    float* out = (float*)d_out;

    const int* row = ei;
    const int* col = ei + N_EDGES;

    // workspace layout. Region A is time-shared: {cnt+base} then csr.
    char* wsb = (char*)d_ws;
    size_t o = 0;
    int*      part     = (int*)(wsb + o);      o += (size_t)N_EDGES * 4;      // 12.8 MB
    char*     regionA  = wsb + o;              o += (size_t)N_EDGES * 4;      // 12.8 MB
    int*      cnt      = (int*)regionA;                                       // [NCH][NB]
    int*      base     = (int*)(regionA + (size_t)NCH * NB * 4);              // [NB][NCH]
    int*      csr      = (int*)regionA;                                       // after place
    int*      bcnt     = (int*)(wsb + o);      o += 1024 * 4;
    int*      offs     = (int*)(wsb + o);      o += 1024 * 4;
    int*      node_off = (int*)(wsb + o);      o += 100352 * 4;
    int*      deg      = (int*)(wsb + o);      o += 100352 * 4;
    float*    dinv     = (float*)(wsb + o);    o += 100352 * 4;
    unsigned* xsh      = (unsigned*)(wsb + o); o += (size_t)N_NODES * 4 * 4;    // 1.6 MB
    unsigned* sBh      = (unsigned*)(wsb + o); o += (size_t)N_NODES * D_H2 * 4; // 3.2 MB
    float*    h2       = (float*)(wsb + o);    o += (size_t)N_NODES * D_H * 4;  // 6.4 MB
    int*      starts   = (int*)(wsb + o);      o += 1024 * 4;

    const int B = 256;
    const int NVB = (N_NODES + B - 1) / B;   // 391

    // ---- build CSR via deterministic two-level scan (no global cursor atomics) ----
    hist_kernel<<<NCH, 512, 0, stream>>>(col, cnt);
    colscan_kernel<<<NB, B, 0, stream>>>(cnt, base, bcnt);
    scan_kernel<<<1, 1024, 0, stream>>>(bcnt, offs);
    place_kernel<<<NCH, 512, 0, stream>>>(row, col, base, offs, part);
    csr_kernel<<<NB, 512, 0, stream>>>(part, offs, csr, node_off, deg, dinv);

    // ---- layer 1: x-space aggregation, fused @W1 + @W2 epilogue ----
    xs_kernel<<<NVB, B, 0, stream>>>(x, dinv, xsh);
    pull1_kernel<<<N_NODES / 8, B, 0, stream>>>(xsh, csr, node_off, deg, dinv,
                                                b1, W1, W2, sBh);
    // ---- layer 2 ----
    pull2_kernel<<<N_NODES / 8, B, 0, stream>>>(sBh, csr, node_off, deg, dinv,
                                                b2, h2);
    // ---- pool + head ----
    starts_kernel<<<NVB, B, 0, stream>>>(batch, starts);
    pool_head_kernel<<<NUM_GRAPHS, B, 0, stream>>>(h2, starts, Wl, bl, out);
}

// Round 20
// 121.381 us; speedup vs baseline: 1.2438x; 1.0839x over previous
//
#include <hip/hip_runtime.h>
#include <hip/hip_fp16.h>
#include <math.h>

#define N_NODES    100000
#define N_EDGES    3200000
#define NUM_GRAPHS 512
#define D_IN       7
#define D_H        16
#define D_H2       8                           // half2 words per node row (16 feats)
#define SHIFT      7
#define BWIDTH     128                         // cols per bucket
#define NB         782                         // ceil(N_NODES / BWIDTH)
#define CHUNK      8192
#define NCH        391                         // ceil(N_EDGES / CHUNK)
#define PC         2                           // chunks per thread (colscan)
#define PB         2                           // buckets per thread (place, 512 thr)
#define TPH        36                          // words/feature-word row per half (32+4; %4==0)
#define HST        (8 * TPH)                   // 288 words per half (pull2, 8-word rows)
#define TP1        36
#define HST1       (4 * TP1)                   // 144 words per half (pull1, 4-word rows)

// ---- pass A: per-chunk bucket histograms (int4 loads; chunk bounds %4==0) ----
__global__ void hist_kernel(const int* __restrict__ col, int* __restrict__ cnt) {
    __shared__ int lh[NB];
    int tid = threadIdx.x;
    for (int i = tid; i < NB; i += blockDim.x) lh[i] = 0;
    __syncthreads();
    int e0 = blockIdx.x * CHUNK;
    int n  = N_EDGES - e0; if (n > CHUNK) n = CHUNK;
    int n4 = n >> 2;
    const int4* cp = (const int4*)(col + e0);
    for (int q = tid; q < n4; q += blockDim.x) {
        int4 v = cp[q];
        atomicAdd(&lh[v.x >> SHIFT], 1);
        atomicAdd(&lh[v.y >> SHIFT], 1);
        atomicAdd(&lh[v.z >> SHIFT], 1);
        atomicAdd(&lh[v.w >> SHIFT], 1);
    }
    __syncthreads();
    int* outp = cnt + (size_t)blockIdx.x * NB;
    for (int i = tid; i < NB; i += blockDim.x) outp[i] = lh[i];
}

// ---- pass B: per-bucket exclusive scan over chunks ----
__global__ void colscan_kernel(const int* __restrict__ cnt, int* __restrict__ base,
                               int* __restrict__ bcnt) {
    __shared__ int ts[256];
    int b = blockIdx.x;
    int tid = threadIdx.x;
    int c0 = tid * PC;
    int vals[PC];
    int sum = 0;
#pragma unroll
    for (int q = 0; q < PC; ++q) {
        int c = c0 + q;
        int v = (c < NCH) ? cnt[(size_t)c * NB + b] : 0;
        vals[q] = v; sum += v;
    }
    ts[tid] = sum;
    __syncthreads();
    for (int st = 1; st < 256; st <<= 1) {
        int v = (tid >= st) ? ts[tid - st] : 0;
        __syncthreads();
        ts[tid] += v;
        __syncthreads();
    }
    int run = ts[tid] - sum;
    int* bp = base + (size_t)b * NCH;
#pragma unroll
    for (int q = 0; q < PC; ++q) {
        int c = c0 + q;
        if (c < NCH) { bp[c] = run; run += vals[q]; }
    }
    if (tid == 0) bcnt[b] = ts[255];
}

// ---- pass C: exclusive scan of bucket totals -> offs ----
__global__ void scan_kernel(const int* __restrict__ bcnt, int* __restrict__ offs) {
    __shared__ int lds[1024];
    int tid = threadIdx.x;
    lds[tid] = (tid < NB) ? bcnt[tid] : 0;
    __syncthreads();
    for (int st = 1; st < 1024; st <<= 1) {
        int v = (tid >= st) ? lds[tid - st] : 0;
        __syncthreads();
        lds[tid] += v;
        __syncthreads();
    }
    if (tid < NB) offs[tid + 1] = lds[tid];
    if (tid == 0) offs[0] = 0;
}

// ---- pass D: place (512 threads, CHUNK=8192, ~76KB LDS, int4 loads) ----
__global__ void place_kernel(const int* __restrict__ row, const int* __restrict__ col,
                             const int* __restrict__ base, const int* __restrict__ offs,
                             int* __restrict__ part) {
    __shared__ int lh[NB];
    __shared__ int sc[NB];
    __shared__ int lb[NB];
    __shared__ int ts[512];
    __shared__ int stage[CHUNK];    // 32 KB
    __shared__ int dstv[CHUNK];     // 32 KB

    int c = blockIdx.x;
    int tid = threadIdx.x;
    int e0 = c * CHUNK;
    int n  = N_EDGES - e0; if (n > CHUNK) n = CHUNK;
    int n4 = n >> 2;
    const int4* cp = (const int4*)(col + e0);
    const int4* rp = (const int4*)(row + e0);

    for (int i = tid; i < NB; i += blockDim.x) lh[i] = 0;
    __syncthreads();
    for (int q = tid; q < n4; q += blockDim.x) {
        int4 v = cp[q];
        atomicAdd(&lh[v.x >> SHIFT], 1);
        atomicAdd(&lh[v.y >> SHIFT], 1);
        atomicAdd(&lh[v.z >> SHIFT], 1);
        atomicAdd(&lh[v.w >> SHIFT], 1);
    }
    __syncthreads();
    int b0 = tid * PB;
    int vals[PB];
    int sum = 0;
#pragma unroll
    for (int q = 0; q < PB; ++q) {
        int b = b0 + q;
        int v = (b < NB) ? lh[b] : 0;
        vals[q] = v; sum += v;
    }
    ts[tid] = sum;
    __syncthreads();
    for (int st = 1; st < 512; st <<= 1) {
        int v = (tid >= st) ? ts[tid - st] : 0;
        __syncthreads();
        ts[tid] += v;
        __syncthreads();
    }
    int run = ts[tid] - sum;
#pragma unroll
    for (int q = 0; q < PB; ++q) {
        int b = b0 + q;
        if (b < NB) {
            sc[b] = run;
            lb[b] = offs[b] + base[(size_t)b * NCH + c];
            run += vals[q];
            lh[b] = 0;
        }
    }
    __syncthreads();
    for (int q = tid; q < n4; q += blockDim.x) {
        int4 cc4 = cp[q];
        int4 rr4 = rp[q];
        int ccs[4] = { cc4.x, cc4.y, cc4.z, cc4.w };
        int rrs[4] = { rr4.x, rr4.y, rr4.z, rr4.w };
#pragma unroll
        for (int t = 0; t < 4; ++t) {
            int cc = ccs[t];
            int b = cc >> SHIFT;
            int rank = atomicAdd(&lh[b], 1);
            int loc = sc[b] + rank;
            stage[loc] = (rrs[t] << SHIFT) | (cc & (BWIDTH - 1));
            dstv[loc]  = lb[b] + rank;
        }
    }
    __syncthreads();
    for (int i = tid; i < n; i += blockDim.x)
        part[dstv[i]] = stage[i];
}

// ---- pass E: per-bucket CSR build + node_off/deg/dinv ----
__global__ void csr_kernel(const int* __restrict__ part, const int* __restrict__ offs,
                           int* __restrict__ csr, int* __restrict__ node_off,
                           int* __restrict__ deg, float* __restrict__ dinv) {
    __shared__ int cnt[BWIDTH];
    __shared__ int scn[BWIDTH];
    __shared__ int cur[BWIDTH];
    int b = blockIdx.x;
    int o0 = offs[b], o1 = offs[b + 1];
    if (threadIdx.x < BWIDTH) cnt[threadIdx.x] = 0;
    __syncthreads();
    for (int j = o0 + threadIdx.x; j < o1; j += blockDim.x)
        atomicAdd(&cnt[part[j] & (BWIDTH - 1)], 1);
    __syncthreads();
    if (threadIdx.x < BWIDTH) scn[threadIdx.x] = cnt[threadIdx.x];
    __syncthreads();
    for (int st = 1; st < BWIDTH; st <<= 1) {
        int v = 0;
        if (threadIdx.x < BWIDTH && threadIdx.x >= st) v = scn[threadIdx.x - st];
        __syncthreads();
        if (threadIdx.x < BWIDTH) scn[threadIdx.x] += v;
        __syncthreads();
    }
    if (threadIdx.x < BWIDTH) {
        int excl = scn[threadIdx.x] - cnt[threadIdx.x];
        cur[threadIdx.x] = excl;
        int c = b * BWIDTH + threadIdx.x;
        if (c < N_NODES) {
            node_off[c] = o0 + excl;
            deg[c] = cnt[threadIdx.x];
            dinv[c] = rsqrtf((float)cnt[threadIdx.x] + 1.0f);   // +1 self-loop
        }
    }
    __syncthreads();
    for (int j = o0 + threadIdx.x; j < o1; j += blockDim.x) {
        int e = part[j];
        int l = e & (BWIDTH - 1);
        int pos = atomicAdd(&cur[l], 1);
        csr[o0 + pos] = e >> SHIFT;
    }
}

// xs[v,:] = dinv[v] * x[v,:], packed 8 halves (7 feats + 0-pad) = 4 words/node
__global__ void xs_kernel(const float* __restrict__ x, const float* __restrict__ dinv,
                          unsigned* __restrict__ xsh) {
    int v = blockIdx.x * blockDim.x + threadIdx.x;
    if (v >= N_NODES) return;
    float dv = dinv[v];
    float xv[8];
#pragma unroll
    for (int j = 0; j < D_IN; ++j) xv[j] = x[v * D_IN + j] * dv;
    xv[7] = 0.f;
#pragma unroll
    for (int w = 0; w < 4; ++w) {
        __half2 p = __floats2half2_rn(xv[2 * w], xv[2 * w + 1]);
        xsh[(size_t)v * 4 + w] = *(unsigned*)&p;
    }
}

// ---- pull1: 2 nodes/wave, 16B x-rows, reg-prefetch pipeline,
//      post-aggregation @W1 then fused @W2 (node-ordered: coalesced writes) ----
__global__ void __launch_bounds__(256, 8)
pull1_kernel(const unsigned* __restrict__ xsh, const int* __restrict__ csr,
             const int* __restrict__ node_off, const int* __restrict__ deg,
             const float* __restrict__ dinv, const float* __restrict__ b1,
             const float* __restrict__ W1, const float* __restrict__ W2,
             unsigned* __restrict__ s2h) {
    __shared__ unsigned stage[4][2 * HST1];   // 4608 B
    __shared__ float aggrow[4][2][8];
    __shared__ float hrow[4][2][D_H];
    int wave = threadIdx.x >> 6;
    int lane = threadIdx.x & 63;
    int h = lane >> 5, l = lane & 31;
    int v = blockIdx.x * 8 + wave * 2 + h;
    int k = l & 15;
    float w1c[D_IN];
#pragma unroll
    for (int j = 0; j < D_IN; ++j) w1c[j] = W1[j * D_H + k];
    float w2c[D_H];
#pragma unroll
    for (int j = 0; j < D_H; ++j) w2c[j] = W2[j * D_H + k];
    int d = deg[v], o0 = node_off[v];
    unsigned* stg = stage[wave] + h * HST1;
    int rg = l >> 3, p = l & 7;
    int w = p >> 1;
    bool hi = (p & 1);
    const uint4* rp = (const uint4*)(stg + w * TP1 + rg * 8);
    float acc = 0.f;
    uint4 a = make_uint4(0u, 0u, 0u, 0u);
    if (l < d) {
        int r = __builtin_nontemporal_load(&csr[o0 + l]);
        a = *(const uint4*)(xsh + (size_t)r * 4);
    }
    for (int base = 0; base < d; base += 32) {
        uint4 an = make_uint4(0u, 0u, 0u, 0u);
        int jn = base + 32 + l;
        if (jn < d) {                          // prefetch next pass (issues early)
            int r = __builtin_nontemporal_load(&csr[o0 + jn]);
            an = *(const uint4*)(xsh + (size_t)r * 4);
        }
        asm volatile("s_waitcnt lgkmcnt(0)" ::: "memory");
        stg[0 * TP1 + l] = a.x;
        stg[1 * TP1 + l] = a.y;
        stg[2 * TP1 + l] = a.z;
        stg[3 * TP1 + l] = a.w;
        asm volatile("s_waitcnt lgkmcnt(0)" ::: "memory");
        uint4 q0 = rp[0], q1 = rp[1];
        unsigned ws[8] = { q0.x, q0.y, q0.z, q0.w, q1.x, q1.y, q1.z, q1.w };
#pragma unroll
        for (int i = 0; i < 8; ++i) {
            __half2 ph = *(__half2*)&ws[i];
            acc += hi ? __high2float(ph) : __low2float(ph);
        }
        a = an;
    }
    acc += __shfl_xor(acc, 8, 64);
    acc += __shfl_xor(acc, 16, 64);   // all 32 lanes: agg for x-feature p
    float dv = dinv[v];
    if (l < 8) aggrow[wave][h][l] = acc;
    asm volatile("s_waitcnt lgkmcnt(0)" ::: "memory");
    uint4 sx = *(const uint4*)(xsh + (size_t)v * 4);
    unsigned sxw[4] = { sx.x, sx.y, sx.z, sx.w };
    const float* ag = aggrow[wave][h];
    float hv = b1[k];
#pragma unroll
    for (int j = 0; j < D_IN; ++j) {
        __half2 ph = *(__half2*)&sxw[j >> 1];
        float xsv = (j & 1) ? __high2float(ph) : __low2float(ph);
        hv += dv * (ag[j] + xsv) * w1c[j];
    }
    hv = fmaxf(hv, 0.f);
    if (l < 16) hrow[wave][h][k] = hv;
    asm volatile("s_waitcnt lgkmcnt(0)" ::: "memory");
    const float4* hp = (const float4*)hrow[wave][h];
    float4 h0 = hp[0], h1 = hp[1], h2 = hp[2], h3 = hp[3];
    float a2 = h0.x * w2c[0] + h0.y * w2c[1] + h0.z * w2c[2] + h0.w * w2c[3]
             + h1.x * w2c[4] + h1.y * w2c[5] + h1.z * w2c[6] + h1.w * w2c[7]
             + h2.x * w2c[8] + h2.y * w2c[9] + h2.z * w2c[10] + h2.w * w2c[11]
             + h3.x * w2c[12] + h3.y * w2c[13] + h3.z * w2c[14] + h3.w * w2c[15];
    a2 *= dv;
    float a2hi = __shfl_xor(a2, 1, 64);
    if (l < 16 && (k & 1) == 0) {
        __half2 pq = __floats2half2_rn(a2, a2hi);
        s2h[(size_t)v * D_H2 + (k >> 1)] = *(unsigned*)&pq;
    }
}

// ---- pull2: 2 nodes/wave, 32B s2-rows, reg-prefetch pipeline (node-ordered) ----
__global__ void __launch_bounds__(256, 8)
pull2_kernel(const unsigned* __restrict__ sh, const int* __restrict__ csr,
             const int* __restrict__ node_off, const int* __restrict__ deg,
             const float* __restrict__ dinv, const float* __restrict__ b2,
             float* __restrict__ h2) {
    __shared__ unsigned stage[4][2 * HST];
    int wave = threadIdx.x >> 6;
    int lane = threadIdx.x & 63;
    int h = lane >> 5, l = lane & 31;
    int v = blockIdx.x * 8 + wave * 2 + h;
    int k = l & 15;
    int d = deg[v], o0 = node_off[v];
    unsigned* stg = stage[wave] + h * HST;
    int g = l >> 4;
    const uint4* rp = (const uint4*)(stg + (k >> 1) * TPH + g * 16);
    bool hi = (k & 1);
    float acc = 0.f;
    uint4 a = make_uint4(0u, 0u, 0u, 0u), b = make_uint4(0u, 0u, 0u, 0u);
    if (l < d) {
        int r = __builtin_nontemporal_load(&csr[o0 + l]);
        const uint4* sp = (const uint4*)(sh + (size_t)r * D_H2);
        a = sp[0];
        b = sp[1];
    }
    for (int base = 0; base < d; base += 32) {
        uint4 an = make_uint4(0u, 0u, 0u, 0u), bn = make_uint4(0u, 0u, 0u, 0u);
        int jn = base + 32 + l;
        if (jn < d) {                          // prefetch next pass
            int r = __builtin_nontemporal_load(&csr[o0 + jn]);
            const uint4* sp = (const uint4*)(sh + (size_t)r * D_H2);
            an = sp[0];
            bn = sp[1];
        }
        asm volatile("s_waitcnt lgkmcnt(0)" ::: "memory");
        stg[0 * TPH + l] = a.x;
        stg[1 * TPH + l] = a.y;
        stg[2 * TPH + l] = a.z;
        stg[3 * TPH + l] = a.w;
        stg[4 * TPH + l] = b.x;
        stg[5 * TPH + l] = b.y;
        stg[6 * TPH + l] = b.z;
        stg[7 * TPH + l] = b.w;
        asm volatile("s_waitcnt lgkmcnt(0)" ::: "memory");
        uint4 q0 = rp[0], q1 = rp[1], q2 = rp[2], q3 = rp[3];
        unsigned ws[16] = { q0.x, q0.y, q0.z, q0.w, q1.x, q1.y, q1.z, q1.w,
                            q2.x, q2.y, q2.z, q2.w, q3.x, q3.y, q3.z, q3.w };
#pragma unroll
        for (int i = 0; i < 16; ++i) {
            __half2 p = *(__half2*)&ws[i];
            acc += hi ? __high2float(p) : __low2float(p);
        }
        a = an; b = bn;
    }
    acc += __shfl_xor(acc, 16, 64);
    if (l < 16) {
        float dv = dinv[v];
        unsigned wsv = sh[(size_t)v * D_H2 + (k >> 1)];
        __half2 ps = *(__half2*)&wsv;
        float selfv = (k & 1) ? __high2float(ps) : __low2float(ps);
        float o = dv * (acc + selfv) + b2[k];
        h2[(size_t)v * D_H + k] = fmaxf(o, 0.f);
    }
}

// batch sorted: starts[g] = first node of graph g
__global__ void starts_kernel(const int* __restrict__ batch, int* __restrict__ starts) {
    int v = blockIdx.x * blockDim.x + threadIdx.x;
    if (v >= N_NODES) return;
    int bv = batch[v];
    int prev = (v == 0) ? -1 : batch[v - 1];
    for (int g = prev + 1; g <= bv; ++g) starts[g] = v;
    if (v == N_NODES - 1) {
        for (int g = bv + 1; g <= NUM_GRAPHS; ++g) starts[g] = N_NODES;
    }
}

// one block per graph: mean-pool h rows then sigmoid(pool @ Wl + bl)
__global__ void pool_head_kernel(const float* __restrict__ h, const int* __restrict__ starts,
                                 const float* __restrict__ Wl, const float* __restrict__ bl,
                                 float* __restrict__ out) {
    int g = blockIdx.x;
    int v0 = starts[g], v1 = starts[g + 1];
    int k = threadIdx.x & 15;
    int vi = threadIdx.x >> 4;
    float acc = 0.f;
    for (int v = v0 + vi; v < v1; v += 16) acc += h[v * D_H + k];
    acc += __shfl_xor(acc, 16, 64);
    acc += __shfl_xor(acc, 32, 64);
    __shared__ float sm[4][D_H];
    int lane = threadIdx.x & 63;
    if (lane < 16) sm[threadIdx.x >> 6][k] = acc;
    __syncthreads();
    if (threadIdx.x < 16) {
        float tot = sm[0][k] + sm[1][k] + sm[2][k] + sm[3][k];
        float cntf = (float)(v1 - v0);
        tot /= fmaxf(cntf, 1.0f);
        float p = tot * Wl[k];
        p += __shfl_xor(p, 1, 64);
        p += __shfl_xor(p, 2, 64);
        p += __shfl_xor(p, 4, 64);
        p += __shfl_xor(p, 8, 64);
        if (k == 0) out[g] = 1.0f / (1.0f + expf(-(p + bl[0])));
    }
}

// ---------------- launch ----------------

extern "C" void kernel_launch(void* const* d_in, const int* in_sizes, int n_in,
                              void* d_out, int out_size, void* d_ws, size_t ws_size,
                              hipStream_t stream) {
    const float* x     = (const float*)d_in[0];
    const int*   ei    = (const int*)d_in[1];   // [2, E]: row then col
    const int*   batch = (const int*)d_in[2];
    const float* W1    = (const float*)d_in[3];
    const float* b1    = (const float*)d_in[4];
    const float* W2    = (const float*)d_in[5];
    const float* b2    = (const float*)d_in[6];
    const float* Wl    = (const float*)d_in[7];
    const float* bl    = (const float*)d_in[8];
    float* out = (float*)d_out;

    const int* row = ei;
    const int* col = ei + N_EDGES;

    // workspace layout. Region A is time-shared: {cnt+base} then csr.
    char* wsb = (char*)d_ws;
    size_t o = 0;
    int*      part     = (int*)(wsb + o);      o += (size_t)N_EDGES * 4;      // 12.8 MB
    char*     regionA  = wsb + o;              o += (size_t)N_EDGES * 4;      // 12.8 MB
    int*      cnt      = (int*)regionA;                                       // [NCH][NB]
    int*      base     = (int*)(regionA + (size_t)NCH * NB * 4);              // [NB][NCH]
    int*      csr      = (int*)regionA;                                       // after place
    int*      bcnt     = (int*)(wsb + o);      o += 1024 * 4;
    int*      offs     = (int*)(wsb + o);      o += 1024 * 4;
    int*      node_off = (int*)(wsb + o);      o += 100352 * 4;
    int*      deg      = (int*)(wsb + o);      o += 100352 * 4;
    float*    dinv     = (float*)(wsb + o);    o += 100352 * 4;
    unsigned* xsh      = (unsigned*)(wsb + o); o += (size_t)N_NODES * 4 * 4;    // 1.6 MB
    unsigned* sBh      = (unsigned*)(wsb + o); o += (size_t)N_NODES * D_H2 * 4; // 3.2 MB
    float*    h2       = (float*)(wsb + o);    o += (size_t)N_NODES * D_H * 4;  // 6.4 MB
    int*      starts   = (int*)(wsb + o);      o += 1024 * 4;

    const int B = 256;
    const int NVB = (N_NODES + B - 1) / B;   // 391

    // ---- build CSR via deterministic two-level scan (no global cursor atomics) ----
    hist_kernel<<<NCH, 512, 0, stream>>>(col, cnt);
    colscan_kernel<<<NB, B, 0, stream>>>(cnt, base, bcnt);
    scan_kernel<<<1, 1024, 0, stream>>>(bcnt, offs);
    place_kernel<<<NCH, 512, 0, stream>>>(row, col, base, offs, part);
    csr_kernel<<<NB, 512, 0, stream>>>(part, offs, csr, node_off, deg, dinv);

    // ---- layer 1: x-space aggregation, fused @W1 + @W2 epilogue ----
    xs_kernel<<<NVB, B, 0, stream>>>(x, dinv, xsh);
    pull1_kernel<<<N_NODES / 8, B, 0, stream>>>(xsh, csr, node_off, deg, dinv,
                                                b1, W1, W2, sBh);
    // ---- layer 2 ----
    pull2_kernel<<<N_NODES / 8, B, 0, stream>>>(sBh, csr, node_off, deg, dinv,
                                                b2, h2);
    // ---- pool + head ----
    starts_kernel<<<NVB, B, 0, stream>>>(batch, starts);
    pool_head_kernel<<<NUM_GRAPHS, B, 0, stream>>>(h2, starts, Wl, bl, out);
}

// Round 22
// 120.588 us; speedup vs baseline: 1.2520x; 1.0066x over previous
//
#include <hip/hip_runtime.h>
#include <hip/hip_fp16.h>
#include <math.h>

#define N_NODES    100000
#define N_EDGES    3200000
#define NUM_GRAPHS 512
#define D_IN       7
#define D_H        16
#define D_H2       8                           // half2 words per node row (16 feats)
#define SHIFT      7
#define BWIDTH     128                         // cols per bucket
#define NB         782                         // ceil(N_NODES / BWIDTH)
#define CHUNK      8192
#define NCH        391                         // ceil(N_EDGES / CHUNK)
#define PC         2                           // chunks per thread (colscan)
#define PB         2                           // buckets per thread (place, 512 thr)
#define TPH        36                          // words/feature-word row per half (32+4; %4==0)
#define HST        (8 * TPH)                   // 288 words per half (pull2, 8-word rows)
#define TP1        36
#define HST1       (4 * TP1)                   // 144 words per half (pull1, 4-word rows)

// ---- pass A: per-chunk bucket histograms (int4 loads; chunk bounds %4==0) ----
__global__ void hist_kernel(const int* __restrict__ col, int* __restrict__ cnt) {
    __shared__ int lh[NB];
    int tid = threadIdx.x;
    for (int i = tid; i < NB; i += blockDim.x) lh[i] = 0;
    __syncthreads();
    int e0 = blockIdx.x * CHUNK;
    int n  = N_EDGES - e0; if (n > CHUNK) n = CHUNK;
    int n4 = n >> 2;
    const int4* cp = (const int4*)(col + e0);
    for (int q = tid; q < n4; q += blockDim.x) {
        int4 v = cp[q];
        atomicAdd(&lh[v.x >> SHIFT], 1);
        atomicAdd(&lh[v.y >> SHIFT], 1);
        atomicAdd(&lh[v.z >> SHIFT], 1);
        atomicAdd(&lh[v.w >> SHIFT], 1);
    }
    __syncthreads();
    int* outp = cnt + (size_t)blockIdx.x * NB;
    for (int i = tid; i < NB; i += blockDim.x) outp[i] = lh[i];
}

// ---- pass B: per-bucket exclusive scan over chunks ----
__global__ void colscan_kernel(const int* __restrict__ cnt, int* __restrict__ base,
                               int* __restrict__ bcnt) {
    __shared__ int ts[256];
    int b = blockIdx.x;
    int tid = threadIdx.x;
    int c0 = tid * PC;
    int vals[PC];
    int sum = 0;
#pragma unroll
    for (int q = 0; q < PC; ++q) {
        int c = c0 + q;
        int v = (c < NCH) ? cnt[(size_t)c * NB + b] : 0;
        vals[q] = v; sum += v;
    }
    ts[tid] = sum;
    __syncthreads();
    for (int st = 1; st < 256; st <<= 1) {
        int v = (tid >= st) ? ts[tid - st] : 0;
        __syncthreads();
        ts[tid] += v;
        __syncthreads();
    }
    int run = ts[tid] - sum;
    int* bp = base + (size_t)b * NCH;
#pragma unroll
    for (int q = 0; q < PC; ++q) {
        int c = c0 + q;
        if (c < NCH) { bp[c] = run; run += vals[q]; }
    }
    if (tid == 0) bcnt[b] = ts[255];
}

// ---- pass C: exclusive scan of bucket totals -> offs ----
__global__ void scan_kernel(const int* __restrict__ bcnt, int* __restrict__ offs) {
    __shared__ int lds[1024];
    int tid = threadIdx.x;
    lds[tid] = (tid < NB) ? bcnt[tid] : 0;
    __syncthreads();
    for (int st = 1; st < 1024; st <<= 1) {
        int v = (tid >= st) ? lds[tid - st] : 0;
        __syncthreads();
        lds[tid] += v;
        __syncthreads();
    }
    if (tid < NB) offs[tid + 1] = lds[tid];
    if (tid == 0) offs[0] = 0;
}

// ---- pass D: place (512 threads, CHUNK=8192, ~76KB LDS, int4 loads) ----
__global__ void place_kernel(const int* __restrict__ row, const int* __restrict__ col,
                             const int* __restrict__ base, const int* __restrict__ offs,
                             int* __restrict__ part) {
    __shared__ int lh[NB];
    __shared__ int sc[NB];
    __shared__ int lb[NB];
    __shared__ int ts[512];
    __shared__ int stage[CHUNK];    // 32 KB
    __shared__ int dstv[CHUNK];     // 32 KB

    int c = blockIdx.x;
    int tid = threadIdx.x;
    int e0 = c * CHUNK;
    int n  = N_EDGES - e0; if (n > CHUNK) n = CHUNK;
    int n4 = n >> 2;
    const int4* cp = (const int4*)(col + e0);
    const int4* rp = (const int4*)(row + e0);

    for (int i = tid; i < NB; i += blockDim.x) lh[i] = 0;
    __syncthreads();
    for (int q = tid; q < n4; q += blockDim.x) {
        int4 v = cp[q];
        atomicAdd(&lh[v.x >> SHIFT], 1);
        atomicAdd(&lh[v.y >> SHIFT], 1);
        atomicAdd(&lh[v.z >> SHIFT], 1);
        atomicAdd(&lh[v.w >> SHIFT], 1);
    }
    __syncthreads();
    int b0 = tid * PB;
    int vals[PB];
    int sum = 0;
#pragma unroll
    for (int q = 0; q < PB; ++q) {
        int b = b0 + q;
        int v = (b < NB) ? lh[b] : 0;
        vals[q] = v; sum += v;
    }
    ts[tid] = sum;
    __syncthreads();
    for (int st = 1; st < 512; st <<= 1) {
        int v = (tid >= st) ? ts[tid - st] : 0;
        __syncthreads();
        ts[tid] += v;
        __syncthreads();
    }
    int run = ts[tid] - sum;
#pragma unroll
    for (int q = 0; q < PB; ++q) {
        int b = b0 + q;
        if (b < NB) {
            sc[b] = run;
            lb[b] = offs[b] + base[(size_t)b * NCH + c];
            run += vals[q];
            lh[b] = 0;
        }
    }
    __syncthreads();
    for (int q = tid; q < n4; q += blockDim.x) {
        int4 cc4 = cp[q];
        int4 rr4 = rp[q];
        int ccs[4] = { cc4.x, cc4.y, cc4.z, cc4.w };
        int rrs[4] = { rr4.x, rr4.y, rr4.z, rr4.w };
#pragma unroll
        for (int t = 0; t < 4; ++t) {
            int cc = ccs[t];
            int b = cc >> SHIFT;
            int rank = atomicAdd(&lh[b], 1);
            int loc = sc[b] + rank;
            stage[loc] = (rrs[t] << SHIFT) | (cc & (BWIDTH - 1));
            dstv[loc]  = lb[b] + rank;
        }
    }
    __syncthreads();
    for (int i = tid; i < n; i += blockDim.x)
        part[dstv[i]] = stage[i];
}

// ---- pass E: per-bucket CSR build + node_off/deg/dinv (int4 part reads) ----
__global__ void csr_kernel(const int* __restrict__ part, const int* __restrict__ offs,
                           int* __restrict__ csr, int* __restrict__ node_off,
                           int* __restrict__ deg, float* __restrict__ dinv) {
    __shared__ int cnt[BWIDTH];
    __shared__ int scn[BWIDTH];
    __shared__ int cur[BWIDTH];
    int b = blockIdx.x;
    int o0 = offs[b], o1 = offs[b + 1];
    int oh = (o0 + 3) & ~3; if (oh > o1) oh = o1;      // 16B-aligned body start
    int nb4 = (o1 - oh) >> 2;                          // int4 body count
    int ot = oh + (nb4 << 2);                          // tail start
    const int4* pp = (const int4*)(part + oh);

    if (threadIdx.x < BWIDTH) cnt[threadIdx.x] = 0;
    __syncthreads();
    // histogram pass: head / int4 body / tail
    for (int j = o0 + threadIdx.x; j < oh; j += blockDim.x)
        atomicAdd(&cnt[part[j] & (BWIDTH - 1)], 1);
    for (int q = threadIdx.x; q < nb4; q += blockDim.x) {
        int4 v = pp[q];
        atomicAdd(&cnt[v.x & (BWIDTH - 1)], 1);
        atomicAdd(&cnt[v.y & (BWIDTH - 1)], 1);
        atomicAdd(&cnt[v.z & (BWIDTH - 1)], 1);
        atomicAdd(&cnt[v.w & (BWIDTH - 1)], 1);
    }
    for (int j = ot + threadIdx.x; j < o1; j += blockDim.x)
        atomicAdd(&cnt[part[j] & (BWIDTH - 1)], 1);
    __syncthreads();
    if (threadIdx.x < BWIDTH) scn[threadIdx.x] = cnt[threadIdx.x];
    __syncthreads();
    for (int st = 1; st < BWIDTH; st <<= 1) {
        int v = 0;
        if (threadIdx.x < BWIDTH && threadIdx.x >= st) v = scn[threadIdx.x - st];
        __syncthreads();
        if (threadIdx.x < BWIDTH) scn[threadIdx.x] += v;
        __syncthreads();
    }
    if (threadIdx.x < BWIDTH) {
        int excl = scn[threadIdx.x] - cnt[threadIdx.x];
        cur[threadIdx.x] = excl;
        int c = b * BWIDTH + threadIdx.x;
        if (c < N_NODES) {
            node_off[c] = o0 + excl;
            deg[c] = cnt[threadIdx.x];
            dinv[c] = rsqrtf((float)cnt[threadIdx.x] + 1.0f);   // +1 self-loop
        }
    }
    __syncthreads();
    // scatter pass: head / int4 body / tail
    for (int j = o0 + threadIdx.x; j < oh; j += blockDim.x) {
        int e = part[j];
        int l = e & (BWIDTH - 1);
        int pos = atomicAdd(&cur[l], 1);
        csr[o0 + pos] = e >> SHIFT;
    }
    for (int q = threadIdx.x; q < nb4; q += blockDim.x) {
        int4 v = pp[q];
        int es[4] = { v.x, v.y, v.z, v.w };
#pragma unroll
        for (int t = 0; t < 4; ++t) {
            int e = es[t];
            int l = e & (BWIDTH - 1);
            int pos = atomicAdd(&cur[l], 1);
            csr[o0 + pos] = e >> SHIFT;
        }
    }
    for (int j = ot + threadIdx.x; j < o1; j += blockDim.x) {
        int e = part[j];
        int l = e & (BWIDTH - 1);
        int pos = atomicAdd(&cur[l], 1);
        csr[o0 + pos] = e >> SHIFT;
    }
}

// xs[v,:] = dinv[v] * x[v,:], packed 8 halves (7 feats + 0-pad) = 4 words/node
__global__ void xs_kernel(const float* __restrict__ x, const float* __restrict__ dinv,
                          unsigned* __restrict__ xsh) {
    int v = blockIdx.x * blockDim.x + threadIdx.x;
    if (v >= N_NODES) return;
    float dv = dinv[v];
    float xv[8];
#pragma unroll
    for (int j = 0; j < D_IN; ++j) xv[j] = x[v * D_IN + j] * dv;
    xv[7] = 0.f;
#pragma unroll
    for (int w = 0; w < 4; ++w) {
        __half2 p = __floats2half2_rn(xv[2 * w], xv[2 * w + 1]);
        xsh[(size_t)v * 4 + w] = *(unsigned*)&p;
    }
}

// ---- pull1: 2 nodes/wave, 16B x-rows, reg-prefetch pipeline,
//      post-aggregation @W1 then fused @W2 (node-ordered: coalesced writes) ----
__global__ void __launch_bounds__(256, 8)
pull1_kernel(const unsigned* __restrict__ xsh, const int* __restrict__ csr,
             const int* __restrict__ node_off, const int* __restrict__ deg,
             const float* __restrict__ dinv, const float* __restrict__ b1,
             const float* __restrict__ W1, const float* __restrict__ W2,
             unsigned* __restrict__ s2h) {
    __shared__ unsigned stage[4][2 * HST1];   // 4608 B
    __shared__ float aggrow[4][2][8];
    __shared__ float hrow[4][2][D_H];
    int wave = threadIdx.x >> 6;
    int lane = threadIdx.x & 63;
    int h = lane >> 5, l = lane & 31;
    int v = blockIdx.x * 8 + wave * 2 + h;
    int k = l & 15;
    float w1c[D_IN];
#pragma unroll
    for (int j = 0; j < D_IN; ++j) w1c[j] = W1[j * D_H + k];
    float w2c[D_H];
#pragma unroll
    for (int j = 0; j < D_H; ++j) w2c[j] = W2[j * D_H + k];
    int d = deg[v], o0 = node_off[v];
    unsigned* stg = stage[wave] + h * HST1;
    int rg = l >> 3, p = l & 7;
    int w = p >> 1;
    bool hi = (p & 1);
    const uint4* rp = (const uint4*)(stg + w * TP1 + rg * 8);
    float acc = 0.f;
    uint4 a = make_uint4(0u, 0u, 0u, 0u);
    if (l < d) {
        int r = __builtin_nontemporal_load(&csr[o0 + l]);
        a = *(const uint4*)(xsh + (size_t)r * 4);
    }
    for (int base = 0; base < d; base += 32) {
        uint4 an = make_uint4(0u, 0u, 0u, 0u);
        int jn = base + 32 + l;
        if (jn < d) {                          // prefetch next pass (issues early)
            int r = __builtin_nontemporal_load(&csr[o0 + jn]);
            an = *(const uint4*)(xsh + (size_t)r * 4);
        }
        asm volatile("s_waitcnt lgkmcnt(0)" ::: "memory");
        stg[0 * TP1 + l] = a.x;
        stg[1 * TP1 + l] = a.y;
        stg[2 * TP1 + l] = a.z;
        stg[3 * TP1 + l] = a.w;
        asm volatile("s_waitcnt lgkmcnt(0)" ::: "memory");
        uint4 q0 = rp[0], q1 = rp[1];
        unsigned ws[8] = { q0.x, q0.y, q0.z, q0.w, q1.x, q1.y, q1.z, q1.w };
#pragma unroll
        for (int i = 0; i < 8; ++i) {
            __half2 ph = *(__half2*)&ws[i];
            acc += hi ? __high2float(ph) : __low2float(ph);
        }
        a = an;
    }
    acc += __shfl_xor(acc, 8, 64);
    acc += __shfl_xor(acc, 16, 64);   // all 32 lanes: agg for x-feature p
    float dv = dinv[v];
    if (l < 8) aggrow[wave][h][l] = acc;
    asm volatile("s_waitcnt lgkmcnt(0)" ::: "memory");
    uint4 sx = *(const uint4*)(xsh + (size_t)v * 4);
    unsigned sxw[4] = { sx.x, sx.y, sx.z, sx.w };
    const float* ag = aggrow[wave][h];
    float hv = b1[k];
#pragma unroll
    for (int j = 0; j < D_IN; ++j) {
        __half2 ph = *(__half2*)&sxw[j >> 1];
        float xsv = (j & 1) ? __high2float(ph) : __low2float(ph);
        hv += dv * (ag[j] + xsv) * w1c[j];
    }
    hv = fmaxf(hv, 0.f);
    if (l < 16) hrow[wave][h][k] = hv;
    asm volatile("s_waitcnt lgkmcnt(0)" ::: "memory");
    const float4* hp = (const float4*)hrow[wave][h];
    float4 h0 = hp[0], h1 = hp[1], h2 = hp[2], h3 = hp[3];
    float a2 = h0.x * w2c[0] + h0.y * w2c[1] + h0.z * w2c[2] + h0.w * w2c[3]
             + h1.x * w2c[4] + h1.y * w2c[5] + h1.z * w2c[6] + h1.w * w2c[7]
             + h2.x * w2c[8] + h2.y * w2c[9] + h2.z * w2c[10] + h2.w * w2c[11]
             + h3.x * w2c[12] + h3.y * w2c[13] + h3.z * w2c[14] + h3.w * w2c[15];
    a2 *= dv;
    float a2hi = __shfl_xor(a2, 1, 64);
    if (l < 16 && (k & 1) == 0) {
        __half2 pq = __floats2half2_rn(a2, a2hi);
        s2h[(size_t)v * D_H2 + (k >> 1)] = *(unsigned*)&pq;
    }
}

// ---- pull2: 2 nodes/wave, 32B s2-rows, reg-prefetch pipeline (node-ordered) ----
__global__ void __launch_bounds__(256, 8)
pull2_kernel(const unsigned* __restrict__ sh, const int* __restrict__ csr,
             const int* __restrict__ node_off, const int* __restrict__ deg,
             const float* __restrict__ dinv, const float* __restrict__ b2,
             float* __restrict__ h2) {
    __shared__ unsigned stage[4][2 * HST];
    int wave = threadIdx.x >> 6;
    int lane = threadIdx.x & 63;
    int h = lane >> 5, l = lane & 31;
    int v = blockIdx.x * 8 + wave * 2 + h;
    int k = l & 15;
    int d = deg[v], o0 = node_off[v];
    unsigned* stg = stage[wave] + h * HST;
    int g = l >> 4;
    const uint4* rp = (const uint4*)(stg + (k >> 1) * TPH + g * 16);
    bool hi = (k & 1);
    float acc = 0.f;
    uint4 a = make_uint4(0u, 0u, 0u, 0u), b = make_uint4(0u, 0u, 0u, 0u);
    if (l < d) {
        int r = __builtin_nontemporal_load(&csr[o0 + l]);
        const uint4* sp = (const uint4*)(sh + (size_t)r * D_H2);
        a = sp[0];
        b = sp[1];
    }
    for (int base = 0; base < d; base += 32) {
        uint4 an = make_uint4(0u, 0u, 0u, 0u), bn = make_uint4(0u, 0u, 0u, 0u);
        int jn = base + 32 + l;
        if (jn < d) {                          // prefetch next pass
            int r = __builtin_nontemporal_load(&csr[o0 + jn]);
            const uint4* sp = (const uint4*)(sh + (size_t)r * D_H2);
            an = sp[0];
            bn = sp[1];
        }
        asm volatile("s_waitcnt lgkmcnt(0)" ::: "memory");
        stg[0 * TPH + l] = a.x;
        stg[1 * TPH + l] = a.y;
        stg[2 * TPH + l] = a.z;
        stg[3 * TPH + l] = a.w;
        stg[4 * TPH + l] = b.x;
        stg[5 * TPH + l] = b.y;
        stg[6 * TPH + l] = b.z;
        stg[7 * TPH + l] = b.w;
        asm volatile("s_waitcnt lgkmcnt(0)" ::: "memory");
        uint4 q0 = rp[0], q1 = rp[1], q2 = rp[2], q3 = rp[3];
        unsigned ws[16] = { q0.x, q0.y, q0.z, q0.w, q1.x, q1.y, q1.z, q1.w,
                            q2.x, q2.y, q2.z, q2.w, q3.x, q3.y, q3.z, q3.w };
#pragma unroll
        for (int i = 0; i < 16; ++i) {
            __half2 p = *(__half2*)&ws[i];
            acc += hi ? __high2float(p) : __low2float(p);
        }
        a = an; b = bn;
    }
    acc += __shfl_xor(acc, 16, 64);
    if (l < 16) {
        float dv = dinv[v];
        unsigned wsv = sh[(size_t)v * D_H2 + (k >> 1)];
        __half2 ps = *(__half2*)&wsv;
        float selfv = (k & 1) ? __high2float(ps) : __low2float(ps);
        float o = dv * (acc + selfv) + b2[k];
        h2[(size_t)v * D_H + k] = fmaxf(o, 0.f);
    }
}

// batch sorted: starts[g] = first node of graph g
__global__ void starts_kernel(const int* __restrict__ batch, int* __restrict__ starts) {
    int v = blockIdx.x * blockDim.x + threadIdx.x;
    if (v >= N_NODES) return;
    int bv = batch[v];
    int prev = (v == 0) ? -1 : batch[v - 1];
    for (int g = prev + 1; g <= bv; ++g) starts[g] = v;
    if (v == N_NODES - 1) {
        for (int g = bv + 1; g <= NUM_GRAPHS; ++g) starts[g] = N_NODES;
    }
}

// one block per graph: mean-pool h rows then sigmoid(pool @ Wl + bl)
__global__ void pool_head_kernel(const float* __restrict__ h, const int* __restrict__ starts,
                                 const float* __restrict__ Wl, const float* __restrict__ bl,
                                 float* __restrict__ out) {
    int g = blockIdx.x;
    int v0 = starts[g], v1 = starts[g + 1];
    int k = threadIdx.x & 15;
    int vi = threadIdx.x >> 4;
    float acc = 0.f;
    for (int v = v0 + vi; v < v1; v += 16) acc += h[v * D_H + k];
    acc += __shfl_xor(acc, 16, 64);
    acc += __shfl_xor(acc, 32, 64);
    __shared__ float sm[4][D_H];
    int lane = threadIdx.x & 63;
    if (lane < 16) sm[threadIdx.x >> 6][k] = acc;
    __syncthreads();
    if (threadIdx.x < 16) {
        float tot = sm[0][k] + sm[1][k] + sm[2][k] + sm[3][k];
        float cntf = (float)(v1 - v0);
        tot /= fmaxf(cntf, 1.0f);
        float p = tot * Wl[k];
        p += __shfl_xor(p, 1, 64);
        p += __shfl_xor(p, 2, 64);
        p += __shfl_xor(p, 4, 64);
        p += __shfl_xor(p, 8, 64);
        if (k == 0) out[g] = 1.0f / (1.0f + expf(-(p + bl[0])));
    }
}

// ---------------- launch ----------------

extern "C" void kernel_launch(void* const* d_in, const int* in_sizes, int n_in,
                              void* d_out, int out_size, void* d_ws, size_t ws_size,
                              hipStream_t stream) {
    const float* x     = (const float*)d_in[0];
    const int*   ei    = (const int*)d_in[1];   // [2, E]: row then col
    const int*   batch = (const int*)d_in[2];
    const float* W1    = (const float*)d_in[3];
    const float* b1    = (const float*)d_in[4];
    const float* W2    = (const float*)d_in[5];
    const float* b2    = (const float*)d_in[6];
    const float* Wl    = (const float*)d_in[7];
    const float* bl    = (const float*)d_in[8];
    float* out = (float*)d_out;

    const int* row = ei;
    const int* col = ei + N_EDGES;

    // workspace layout. Region A is time-shared: {cnt+base} then csr.
    char* wsb = (char*)d_ws;
    size_t o = 0;
    int*      part     = (int*)(wsb + o);      o += (size_t)N_EDGES * 4;      // 12.8 MB
    char*     regionA  = wsb + o;              o += (size_t)N_EDGES * 4;      // 12.8 MB
    int*      cnt      = (int*)regionA;                                       // [NCH][NB]
    int*      base     = (int*)(regionA + (size_t)NCH * NB * 4);              // [NB][NCH]
    int*      csr      = (int*)regionA;                                       // after place
    int*      bcnt     = (int*)(wsb + o);      o += 1024 * 4;
    int*      offs     = (int*)(wsb + o);      o += 1024 * 4;
    int*      node_off = (int*)(wsb + o);      o += 100352 * 4;
    int*      deg      = (int*)(wsb + o);      o += 100352 * 4;
    float*    dinv     = (float*)(wsb + o);    o += 100352 * 4;
    unsigned* xsh      = (unsigned*)(wsb + o); o += (size_t)N_NODES * 4 * 4;    // 1.6 MB
    unsigned* sBh      = (unsigned*)(wsb + o); o += (size_t)N_NODES * D_H2 * 4; // 3.2 MB
    float*    h2       = (float*)(wsb + o);    o += (size_t)N_NODES * D_H * 4;  // 6.4 MB
    int*      starts   = (int*)(wsb + o);      o += 1024 * 4;

    const int B = 256;
    const int NVB = (N_NODES + B - 1) / B;   // 391

    // ---- build CSR via deterministic two-level scan (no global cursor atomics) ----
    hist_kernel<<<NCH, 512, 0, stream>>>(col, cnt);
    colscan_kernel<<<NB, B, 0, stream>>>(cnt, base, bcnt);
    scan_kernel<<<1, 1024, 0, stream>>>(bcnt, offs);
    place_kernel<<<NCH, 512, 0, stream>>>(row, col, base, offs, part);
    csr_kernel<<<NB, 512, 0, stream>>>(part, offs, csr, node_off, deg, dinv);

    // ---- layer 1: x-space aggregation, fused @W1 + @W2 epilogue ----
    xs_kernel<<<NVB, B, 0, stream>>>(x, dinv, xsh);
    pull1_kernel<<<N_NODES / 8, B, 0, stream>>>(xsh, csr, node_off, deg, dinv,
                                                b1, W1, W2, sBh);
    // ---- layer 2 ----
    pull2_kernel<<<N_NODES / 8, B, 0, stream>>>(sBh, csr, node_off, deg, dinv,
                                                b2, h2);
    // ---- pool + head ----
    starts_kernel<<<NVB, B, 0, stream>>>(batch, starts);
    pool_head_kernel<<<NUM_GRAPHS, B, 0, stream>>>(h2, starts, Wl, bl, out);
}